// Round 19
// baseline (23.747 us; speedup 1.0000x reference)
//
#include <hip/hip_runtime.h>
#include <limits.h>

// BKT: B=4096 students, T=512 timesteps, K=2048 skills.
// R19: BARRIER-FREE, wave-private chains. R15/R16/R18 (three structures)
// all plateau at ~14us; shared trait = barrier-lockstep phases. Here each
// WAVE owns one student with private LDS tables -> no __syncthreads at all:
//  - per-wave head table hashed to 256 entries (1KB) + 512 nodes (2KB);
//    node = [21:11] skill (alien filter, R12 lesson), [10] resp, [9:0] prev.
//  - intra-wave ordering = program order (DS pipe in-order per wave);
//    sched_barrier(0) pins compiler phase order.
//  - total work = 4096 waves = 16/CU < resident slots -> ALL waves run
//    concurrently; wall ~ one wave's serial path + launch.
//  - 8 timesteps/lane walked as 4 sequential dual-interleaved walks
//    (register-lean, R17 spill lesson).
// Kept: lazy t/g/s, k0 gathers between build and walk, min1/min2 capture
// (filtered rescan only rank>=3), coalesced per-wave loads/stores.
// LDS 12KB/block (4 waves x 3KB); no launch_bounds pin needed (4 blocks/CU
// resident covers all 16 work-waves/CU).

#define BKT_B 4096
#define BKT_T 512
#define BKT_K 2048
#define BLK   256
#define WPB   4               // waves (students) per block
#define TPL   8               // timesteps per lane
#define HASH  256
#define PTR_END 0x3FF

__device__ __forceinline__ float bkt_update(float p, int rbit, float ss,
                                            float gg, float tt) {
  float num, den;
  if (rbit) {                // correct response
    num = p * (1.0f - ss);
    den = num + (1.0f - p) * gg;
  } else {                   // incorrect response
    num = p * ss;
    den = num + (1.0f - p) * (1.0f - gg);
  }
  const float q = num / den; // Bayesian posterior
  return q + (1.0f - q) * tt;// learning transition
}

__global__ void bkt_kernel(
    const int* __restrict__ skills,
    const float* __restrict__ resp,
    const float* __restrict__ k0,
    const float* __restrict__ tp,
    const float* __restrict__ gp,
    const float* __restrict__ sp,
    float* __restrict__ out) {
  __shared__ int head_s[WPB][HASH];   // 4KB: per-wave hashed heads
  __shared__ int node_s[WPB][BKT_T];  // 8KB: per-wave packed nodes

  const int wid  = threadIdx.x >> 6;          // wave id in block
  const int lane = threadIdx.x & 63;
  const int stu  = blockIdx.x * WPB + wid;    // this wave's student
  const int base = stu * BKT_T;

  // coalesced per-wave loads of this student's row (8 t's per lane)
  int sk[TPL], rb[TPL];
#pragma unroll
  for (int u = 0; u < TPL; ++u) {
    const int t = lane + 64 * u;
    sk[u] = skills[base + t];
    rb[u] = resp[base + t] > 0.5f ? 1 : 0;
  }

  // per-wave head init: 256 ints / 64 lanes = one int4 store per lane
  ((int4*)&head_s[wid][0])[lane] = make_int4(-1, -1, -1, -1);
  __builtin_amdgcn_sched_barrier(0);   // pin phase order (no HW barrier)

  // build hashed per-skill lists (arrival order arbitrary; wave-private)
#pragma unroll
  for (int u = 0; u < TPL; ++u) {
    const int t = lane + 64 * u;
    const int s_ = sk[u];
    const int old = atomicExch(&head_s[wid][s_ & (HASH - 1)], t);
    node_s[wid][t] = ((old < 0) ? PTR_END : old) | (rb[u] << 10) | (s_ << 11);
  }
  __builtin_amdgcn_sched_barrier(0);   // build complete (program order)

  // k0 gathers issued now: 8 independent scattered loads, hidden by walks
  float k0v[TPL];
#pragma unroll
  for (int u = 0; u < TPL; ++u)
    k0v[u] = k0[sk[u]];

  // 4 sequential dual-interleaved walks (pairs 2c, 2c+1)
#pragma unroll
  for (int c = 0; c < TPL / 2; ++c) {
    const int ua = 2 * c, ub = 2 * c + 1;
    const int ta = lane + 64 * ua, tb = lane + 64 * ub;
    const int sa = sk[ua], sb = sk[ub];
    const int heada = head_s[wid][sa & (HASH - 1)];
    const int headb = head_s[wid][sb & (HASH - 1)];

    int ja = heada, jb = headb;
    int ranka = 0, rankb = 0;
    int a1 = INT_MAX, a2 = INT_MAX, an1 = 0, an2 = 0;  // min1/min2 (ta)
    int b1 = INT_MAX, b2 = INT_MAX, bn1 = 0, bn2 = 0;  // min1/min2 (tb)
    while ((ja >= 0) || (jb >= 0)) {
      if (ja >= 0) {
        const int nd = node_s[wid][ja];
        if (ja < ta && (nd >> 11) == sa) {
          ++ranka;
          if (ja < a1)      { a2 = a1; an2 = an1; a1 = ja; an1 = nd; }
          else if (ja < a2) { a2 = ja; an2 = nd; }
        }
        const int nx = nd & PTR_END;
        ja = (nx == PTR_END) ? -1 : nx;
      }
      if (jb >= 0) {
        const int nd = node_s[wid][jb];
        if (jb < tb && (nd >> 11) == sb) {
          ++rankb;
          if (jb < b1)      { b2 = b1; bn2 = bn1; b1 = jb; bn1 = nd; }
          else if (jb < b2) { b2 = jb; bn2 = nd; }
        }
        const int nx = nd & PTR_END;
        jb = (nx == PTR_END) ? -1 : nx;
      }
    }

    // ---- replay ta ----
    float pa = k0v[ua];
    if (ranka > 0) {
      const float ss = sp[sa];
      const float gg = gp[sa];
      const float tt = tp[sa];
      pa = bkt_update(pa, (an1 >> 10) & 1, ss, gg, tt);
      if (ranka > 1) {
        pa = bkt_update(pa, (an2 >> 10) & 1, ss, gg, tt);
        int cur = a2;
        for (int rd = 2; rd < ranka; ++rd) {   // rare rank>=3 rescan
          int best = INT_MAX, bestnode = 0;
          for (int j = heada; j >= 0; ) {
            const int nd = node_s[wid][j];
            if (j < ta && j > cur && j < best && (nd >> 11) == sa) {
              best = j; bestnode = nd;
            }
            const int nx = nd & PTR_END;
            j = (nx == PTR_END) ? -1 : nx;
          }
          pa = bkt_update(pa, (bestnode >> 10) & 1, ss, gg, tt);
          cur = best;
        }
      }
    }
    out[base + ta] = pa;                 // coalesced per-wave store

    // ---- replay tb ----
    float pb = k0v[ub];
    if (rankb > 0) {
      const float ss = sp[sb];
      const float gg = gp[sb];
      const float tt = tp[sb];
      pb = bkt_update(pb, (bn1 >> 10) & 1, ss, gg, tt);
      if (rankb > 1) {
        pb = bkt_update(pb, (bn2 >> 10) & 1, ss, gg, tt);
        int cur = b2;
        for (int rd = 2; rd < rankb; ++rd) {
          int best = INT_MAX, bestnode = 0;
          for (int j = headb; j >= 0; ) {
            const int nd = node_s[wid][j];
            if (j < tb && j > cur && j < best && (nd >> 11) == sb) {
              best = j; bestnode = nd;
            }
            const int nx = nd & PTR_END;
            j = (nx == PTR_END) ? -1 : nx;
          }
          pb = bkt_update(pb, (bestnode >> 10) & 1, ss, gg, tt);
          cur = best;
        }
      }
    }
    out[base + tb] = pb;                 // coalesced per-wave store
  }
}

extern "C" void kernel_launch(void* const* d_in, const int* in_sizes, int n_in,
                              void* d_out, int out_size, void* d_ws, size_t ws_size,
                              hipStream_t stream) {
  const int*   skills = (const int*)d_in[0];
  const float* resp   = (const float*)d_in[1];
  const float* k0     = (const float*)d_in[2];
  const float* tp     = (const float*)d_in[3];
  const float* gp     = (const float*)d_in[4];
  const float* sp     = (const float*)d_in[5];
  float* out = (float*)d_out;

  bkt_kernel<<<BKT_B / WPB, BLK, 0, stream>>>(skills, resp, k0, tp, gp, sp, out);
}

// Round 20
// 13.921 us; speedup vs baseline: 1.7058x; 1.7058x over previous
//
#include <hip/hip_runtime.h>
#include <limits.h>

// BKT: B=4096 students, T=512 timesteps, K=2048 skills.
// R20 = R15 verbatim (session best, 13.99us). R19's barrier-free wave-
// private variant regressed to 23.7us -> barriers were not the constraint;
// the ~14us plateau decomposes as: launch/graph ~2.3us, scattered-gather L1
// line throughput ~3us, LDS walk dependent latency ~5us (partially hidden),
// streaming+issue+barriers ~3us. All components attacked at least once
// across R1-R19; this restores the fastest verified structure:
//  - one block per student, 256 thr, t0=tid, t1=tid+256;
//  - direct-mapped 2048-entry head table + packed nodes {resp, prev};
//  - dual-chain interleaved walk (2 dependent ds_read streams in flight),
//    min1/min2 capture -> rescan only rank>=3 (~0.3% lanes);
//  - k0 gathers pre-walk, t/g/s gathers lazy (rank>0 lanes only);
//  - LDS 10KB, launch_bounds(256,8) -> 8 blocks/CU = 32 waves/CU.

#define BKT_B 4096
#define BKT_T 512
#define BKT_K 2048
#define BLK   256
#define PTR_END 0x3FF

__device__ __forceinline__ float bkt_update(float p, int rbit, float ss,
                                            float gg, float tt) {
  float num, den;
  if (rbit) {                // correct response
    num = p * (1.0f - ss);
    den = num + (1.0f - p) * gg;
  } else {                   // incorrect response
    num = p * ss;
    den = num + (1.0f - p) * (1.0f - gg);
  }
  const float q = num / den; // Bayesian posterior
  return q + (1.0f - q) * tt;// learning transition
}

__global__ __launch_bounds__(BLK, 8) void bkt_kernel(
    const int* __restrict__ skills,
    const float* __restrict__ resp,
    const float* __restrict__ k0,
    const float* __restrict__ tp,
    const float* __restrict__ gp,
    const float* __restrict__ sp,
    float* __restrict__ out) {
  __shared__ int head_s[BKT_K];  // 8KB direct-mapped: last arrival, -1 empty
  __shared__ int node_s[BKT_T];  // 2KB packed {resp bit, prev ptr}

  const int b = blockIdx.x;
  const int base = b * BKT_T;
  const int tid = threadIdx.x;
  const int t0 = tid;
  const int t1 = tid + BLK;

  // coalesced row loads; k0 gathers issued early (hide under init/build)
  const int   sk0 = skills[base + t0];
  const int   sk1 = skills[base + t1];
  const float rr0 = resp[base + t0];
  const float rr1 = resp[base + t1];
  const float k00 = k0[sk0];
  const float k01 = k0[sk1];

  // head init: 2048 ints = two int4 stores per thread
  {
    int4* h4 = (int4*)head_s;
    h4[tid] = make_int4(-1, -1, -1, -1);
    h4[tid + BLK] = make_int4(-1, -1, -1, -1);
  }
  __syncthreads();

  // build per-skill linked lists (arrival order arbitrary)
  {
    const int old0 = atomicExch(&head_s[sk0], t0);
    node_s[t0] = ((old0 < 0) ? PTR_END : old0) | ((rr0 > 0.5f ? 1 : 0) << 10);
    const int old1 = atomicExch(&head_s[sk1], t1);
    node_s[t1] = ((old1 < 0) ? PTR_END : old1) | ((rr1 > 0.5f ? 1 : 0) << 10);
  }
  __syncthreads();

  // dual-chain interleaved walk: both timesteps' chains advance together
  const int head0 = head_s[sk0];
  const int head1 = head_s[sk1];
  int j0 = head0, j1 = head1;
  int rank0 = 0, rank1 = 0;
  int a0 = INT_MAX, b0 = INT_MAX, an0 = 0, bn0 = 0;  // min1/min2 (t0)
  int a1 = INT_MAX, b1 = INT_MAX, an1 = 0, bn1 = 0;  // min1/min2 (t1)
  while ((j0 >= 0) || (j1 >= 0)) {
    if (j0 >= 0) {
      const int nd = node_s[j0];
      if (j0 < t0) {
        ++rank0;
        if (j0 < a0)      { b0 = a0; bn0 = an0; a0 = j0; an0 = nd; }
        else if (j0 < b0) { b0 = j0; bn0 = nd; }
      }
      const int nx = nd & PTR_END;
      j0 = (nx == PTR_END) ? -1 : nx;
    }
    if (j1 >= 0) {
      const int nd = node_s[j1];
      if (j1 < t1) {
        ++rank1;
        if (j1 < a1)      { b1 = a1; bn1 = an1; a1 = j1; an1 = nd; }
        else if (j1 < b1) { b1 = j1; bn1 = nd; }
      }
      const int nx = nd & PTR_END;
      j1 = (nx == PTR_END) ? -1 : nx;
    }
  }

  // ---- t0 replay ----
  float p0 = k00;
  if (rank0 > 0) {
    const float ss = sp[sk0];
    const float gg = gp[sk0];
    const float tt = tp[sk0];
    p0 = bkt_update(p0, (an0 >> 10) & 1, ss, gg, tt);
    if (rank0 > 1) {
      p0 = bkt_update(p0, (bn0 >> 10) & 1, ss, gg, tt);
      int cur = b0;
      for (int rd = 2; rd < rank0; ++rd) {   // rank>=3 only (~0.3% lanes)
        int best = INT_MAX, bestnode = 0;
        for (int j = head0; j >= 0; ) {
          const int nd = node_s[j];
          if (j < t0 && j > cur && j < best) { best = j; bestnode = nd; }
          const int nx = nd & PTR_END;
          j = (nx == PTR_END) ? -1 : nx;
        }
        p0 = bkt_update(p0, (bestnode >> 10) & 1, ss, gg, tt);
        cur = best;
      }
    }
  }
  out[base + t0] = p0;                 // emit pre-update mastery

  // ---- t1 replay ----
  float p1 = k01;
  if (rank1 > 0) {
    const float ss = sp[sk1];
    const float gg = gp[sk1];
    const float tt = tp[sk1];
    p1 = bkt_update(p1, (an1 >> 10) & 1, ss, gg, tt);
    if (rank1 > 1) {
      p1 = bkt_update(p1, (bn1 >> 10) & 1, ss, gg, tt);
      int cur = b1;
      for (int rd = 2; rd < rank1; ++rd) {
        int best = INT_MAX, bestnode = 0;
        for (int j = head1; j >= 0; ) {
          const int nd = node_s[j];
          if (j < t1 && j > cur && j < best) { best = j; bestnode = nd; }
          const int nx = nd & PTR_END;
          j = (nx == PTR_END) ? -1 : nx;
        }
        p1 = bkt_update(p1, (bestnode >> 10) & 1, ss, gg, tt);
        cur = best;
      }
    }
  }
  out[base + t1] = p1;                 // emit pre-update mastery
}

extern "C" void kernel_launch(void* const* d_in, const int* in_sizes, int n_in,
                              void* d_out, int out_size, void* d_ws, size_t ws_size,
                              hipStream_t stream) {
  const int*   skills = (const int*)d_in[0];
  const float* resp   = (const float*)d_in[1];
  const float* k0     = (const float*)d_in[2];
  const float* tp     = (const float*)d_in[3];
  const float* gp     = (const float*)d_in[4];
  const float* sp     = (const float*)d_in[5];
  float* out = (float*)d_out;

  bkt_kernel<<<BKT_B, BLK, 0, stream>>>(skills, resp, k0, tp, gp, sp, out);
}